// Round 5
// baseline (145.921 us; speedup 1.0000x reference)
//
#include <hip/hip_runtime.h>
#include <hip/hip_bf16.h>
#include <math.h>

// Problem constants
#define P_TOTAL 18378
// param breakpoints (floats): w1 [0,400), b1 [400,416), w2 [416,13216),
// b2 [13216,13248), w3 [13248,18368), b3 [18368,18378)

typedef __attribute__((ext_vector_type(8))) short short8;
typedef __attribute__((ext_vector_type(4))) float float4v;
typedef __attribute__((ext_vector_type(16))) float float16;

__device__ __forceinline__ unsigned short f2bf(float f) {
    union { float f; unsigned u; } v; v.f = f;
    unsigned r = v.u + 0x7fffu + ((v.u >> 16) & 1u);
    return (unsigned short)(r >> 16);
}
__device__ __forceinline__ float bf2f(unsigned short h) {
    union { unsigned u; float f; } v; v.u = ((unsigned)h) << 16;
    return v.f;
}

// ---------------- Kernel 1 (front): conv1 GEMM w/ inline im2col + w2 swizzle ----------------
// blocks 0..511: (img, init-group) conv1 as K=32 MFMA GEMM, pool in-register.
//   A = im2col pixels (row = pp*4+q), B = w1 (16 co). D: col=co, row=(lane>>4)*4+reg
//   = the 4 quad pixels of pooled pixel pp -> pooling = 3 in-register fmax.
// blocks 512..575: swizzle conv2 weights -> bf16 wswz[init][tap][co=32][cin=16].
#define B_ROW 40   // im2col LDS row stride (elems)
__global__ __launch_bounds__(256) void front_kernel(
        const float* __restrict__ params,
        const float* __restrict__ batch,
        unsigned short* __restrict__ wswz,     // [init][25*32*16] bf16
        unsigned short* __restrict__ act1) {   // [pair][144 pix][16 cin] bf16
    __shared__ unsigned short blds[576 * B_ROW];   // 46080 B (im2col)
    __shared__ unsigned short alds[16 * 512];      // 16384 B (w1, 16 inits)
    __shared__ float img[784];                     // 3136 B  (total 65600 B)
    int blk = blockIdx.x;
    int t = threadIdx.x;

    if (blk >= 512) {   // w2 swizzle path
        int i = blk - 512;
        const float* w2 = params + (size_t)i * P_TOTAL + 416;   // [co32][cin16][5][5]
        unsigned short* dst = wswz + (size_t)i * 12800;
        for (int k = t; k < 12800; k += 256) {
            int co = k / 400;
            int r = k - co * 400;
            int cin = r / 25;
            int s = r - cin * 25;   // s = ky*5+kx
            dst[(s * 32 + co) * 16 + cin] = f2bf(w2[k]);
        }
        return;
    }

    int j  = blk >> 2;       // image
    int ig = blk & 3;        // init group (16 inits)

    // phase 1: load image + convert w1 -> alds (independent)
    {
        const float* ip = batch + j * 784;
        for (int k = t; k < 784; k += 256) img[k] = ip[k];
        for (int e = t; e < 8192; e += 256) {
            int il = e >> 9, r = e & 511;
            int m = r >> 5, k = r & 31;
            int init = ig * 16 + il;
            alds[il * 512 + m * 32 + k] =
                (k < 25) ? f2bf(params[(size_t)init * P_TOTAL + m * 25 + k]) : (unsigned short)0;
        }
    }
    __syncthreads();
    // phase 2: im2col img (LDS) -> blds. c = pp*4+q, k = ky*5+kx (zeros 25..31).
    for (int task = t; task < 2304; task += 256) {
        int c = task >> 2, kh = task & 3;
        int pp = c >> 2, q = c & 3;
        int py = pp / 12, px = pp - py * 12;
        int y0 = 2 * py + (q >> 1);
        int x0 = 2 * px + (q & 1);
        unsigned short ov[8] __attribute__((aligned(16)));
#pragma unroll
        for (int u = 0; u < 8; ++u) {
            int k = kh * 8 + u;
            float v = 0.f;
            if (k < 25) {
                int ky = k / 5, kx = k - ky * 5;
                v = img[(y0 + ky) * 28 + x0 + kx];
            }
            ov[u] = f2bf(v);
        }
        *(uint4*)(blds + c * B_ROW + kh * 8) = *(const uint4*)ov;
    }
    __syncthreads();

    int w = t >> 6, lane = t & 63;
    int co = lane & 15;
    int h = lane >> 4;

    short8 wfr[4];
    float bias[4];
    unsigned short* obase[4];
#pragma unroll
    for (int mt = 0; mt < 4; ++mt) {
        int il = w * 4 + mt;
        int init = ig * 16 + il;
        wfr[mt] = *(const short8*)(alds + il * 512 + co * 32 + h * 8);
        bias[mt] = params[(size_t)init * P_TOTAL + 400 + co];
        obase[mt] = act1 + ((size_t)(init * 128 + j) * 144 + h) * 16 + co;
    }

#pragma unroll 4
    for (int nt = 0; nt < 36; ++nt) {
        short8 afr = *(const short8*)(blds + (nt * 16 + co) * B_ROW + h * 8);
#pragma unroll
        for (int mt = 0; mt < 4; ++mt) {
            float4v acc = {0.f, 0.f, 0.f, 0.f};
            acc = __builtin_amdgcn_mfma_f32_16x16x32_bf16(afr, wfr[mt], acc, 0, 0, 0);
            float v = fmaxf(fmaxf(acc[0], acc[1]), fmaxf(acc[2], acc[3]));
            v = fmaxf(v + bias[mt], 0.f);
            obase[mt][(size_t)nt * 64] = f2bf(v);   // pix = nt*4+h
        }
    }
}

// ---------------- Kernel 2 (tail): conv2 MFMA + pool + dense + log_softmax ----------------
// Block = (init, 4-image group), 4 waves, wave w = image w.
// conv2: 25 taps x mfma_32x32x16 (K=16 cin), two 32x32 acc tiles (64 conv pixels).
// After pooling, lane L holds features f = L*8..L*8+7 of its image -> dense runs
// entirely in registers + wave shuffles; output written directly.
#define W_CO_STRIDE 20          // wlds co stride (elems): bank-uniform A-frag reads
#define W_TAP_STRIDE (32 * W_CO_STRIDE)   // 640 elems
#define A1_PIX_STRIDE 24        // a1s pixel stride (elems)
#define IMG_LDS (144 * 24)      // 3456 elems per image
__global__ __launch_bounds__(256) void tail_kernel(
        const float* __restrict__ params,
        const unsigned short* __restrict__ act1,   // [pair][144][16] bf16
        const unsigned short* __restrict__ wswz,   // [init][25][32][16] bf16
        float* __restrict__ out) {                 // [init][img][10] f32
    __shared__ char smem[65280];
    unsigned short* wlds = (unsigned short*)smem;            // 16000 elems = 32000 B
    unsigned short* a1s  = (unsigned short*)(smem + 32000);  // 13824 elems = 27648 B
    float* scratch       = (float*)(smem + 32000);           // 4*2080 f32 = 33280 B (reuses a1s)

    int b = blockIdx.x;
    int i = b >> 5;           // init
    int g = b & 31;           // image group
    int jbase = g * 4;
    int t = threadIdx.x;
    int w = t >> 6;           // wave = image index within group
    int lane = t & 63;

    { // stage weights with padded co stride
        const uint4* src = (const uint4*)(wswz + (size_t)i * 12800);
        for (int k = t; k < 1600; k += 256) {
            int tap = k >> 6, r = k & 63;
            int co = r >> 1, h2 = r & 1;
            *(uint4*)(wlds + tap * W_TAP_STRIDE + co * W_CO_STRIDE + h2 * 8) = src[k];
        }
    }
    { // stage act1 (4 images) with pad
        for (int k = t; k < 1152; k += 256) {
            int img = k / 288;
            int rem = k - img * 288;
            int pix = rem >> 1;
            int h2  = rem & 1;
            const uint4* src = (const uint4*)(act1 +
                ((size_t)(i * 128 + jbase + img) * 144 + pix) * 16 + h2 * 8);
            *(uint4*)(a1s + img * IMG_LDS + pix * A1_PIX_STRIDE + h2 * 8) = *src;
        }
    }
    __syncthreads();

    int n = lane & 31;
    int h = lane >> 5;
    const short8* aptr = (const short8*)(wlds + n * W_CO_STRIDE + h * 8);
    int y0 = n >> 3, x0 = n & 7;
    const unsigned short* bbase = a1s + w * IMG_LDS;
    const short8* bptr0 = (const short8*)(bbase + ((y0    ) * 12 + x0) * A1_PIX_STRIDE + h * 8);
    const short8* bptr1 = (const short8*)(bbase + ((y0 + 4) * 12 + x0) * A1_PIX_STRIDE + h * 8);

    float16 acc0 = {};
    float16 acc1 = {};
#pragma unroll
    for (int ky = 0; ky < 5; ++ky) {
#pragma unroll
        for (int kx = 0; kx < 5; ++kx) {
            int tap = ky * 5 + kx;
            short8 af = aptr[tap * (W_TAP_STRIDE / 8)];
            int bo = (ky * 12 + kx) * 3;
            short8 b0 = bptr0[bo];
            short8 b1 = bptr1[bo];
            acc0 = __builtin_amdgcn_mfma_f32_32x32x16_bf16(af, b0, acc0, 0, 0, 0);
            acc1 = __builtin_amdgcn_mfma_f32_32x32x16_bf16(af, b1, acc1, 0, 0, 0);
        }
    }
    __syncthreads();   // all waves done reading a1s/wlds before scratch overwrites

    // spill acc to LDS (stride-65 pad), same-wave ordering -> no barrier
    float* sw = scratch + w * 2080;
#pragma unroll
    for (int r = 0; r < 16; ++r) {
        int co = (r & 3) + 8 * (r >> 2) + 4 * h;
        sw[co * 65 + n]      = acc0[r];
        sw[co * 65 + 32 + n] = acc1[r];
    }

    // pool 2x2 + bias + ReLU; lane L ends with features f = L*8..L*8+7 (f = co2*16+pp)
    int co2 = lane >> 1;
    int ppb = (lane & 1) * 8;
    float bias2 = params[(size_t)i * P_TOTAL + 13216 + co2];
    float xr[8];
#pragma unroll
    for (int it = 0; it < 8; ++it) {
        int pp = ppb + it;
        int py = pp >> 2, px = pp & 3;
        const float* s = sw + co2 * 65 + (py * 2) * 8 + px * 2;
        float v = fmaxf(fmaxf(s[0], s[1]), fmaxf(s[8], s[9]));
        xr[it] = fmaxf(v + bias2, 0.f);
    }

    // dense (10x512) + log_softmax, all in registers + shuffles
    const float* wp = params + (size_t)i * P_TOTAL + 13248 + lane * 8;
    float acc[10];
#pragma unroll
    for (int o = 0; o < 10; ++o) {
        const float* wv = wp + o * 512;
        float a = 0.f;
#pragma unroll
        for (int k = 0; k < 8; ++k) a = fmaf(xr[k], wv[k], a);
#pragma unroll
        for (int d = 32; d >= 1; d >>= 1) a += __shfl_xor(a, d, 64);
        acc[o] = a;
    }
    const float* bp = params + (size_t)i * P_TOTAL + 18368;
    float m = -3.4e38f;
#pragma unroll
    for (int o = 0; o < 10; ++o) { acc[o] += bp[o]; m = fmaxf(m, acc[o]); }
    float ssum = 0.f;
#pragma unroll
    for (int o = 0; o < 10; ++o) ssum += expf(acc[o] - m);
    float ls = logf(ssum) + m;
    if (lane == 0) {
        int j = jbase + w;
        float* op = out + ((size_t)i * 128 + j) * 10;
#pragma unroll
        for (int o = 0; o < 10; ++o) op[o] = acc[o] - ls;
    }
}

extern "C" void kernel_launch(void* const* d_in, const int* in_sizes, int n_in,
                              void* d_out, int out_size, void* d_ws, size_t ws_size,
                              hipStream_t stream) {
    const float* params = (const float*)d_in[0];   // (64, 18378) fp32
    const float* batch  = (const float*)d_in[1];   // (128, 1, 28, 28) fp32
    float* out = (float*)d_out;                    // (64, 128, 10) fp32

    // workspace: act1 64*128*144*16 bf16 = 37,748,736 B ; wswz 64*12800 bf16 = 1,638,400 B
    unsigned short* act1 = (unsigned short*)d_ws;
    unsigned short* wswz = act1 + (size_t)64 * 128 * 2304;

    front_kernel<<<576, 256, 0, stream>>>(params, batch, wswz, act1);
    tail_kernel<<<2048, 256, 0, stream>>>(params, act1, wswz, out);
}

// Round 6
// 119.661 us; speedup vs baseline: 1.2194x; 1.2194x over previous
//
#include <hip/hip_runtime.h>
#include <hip/hip_bf16.h>
#include <math.h>

// Problem constants
#define P_TOTAL 18378
// param breakpoints (floats): w1 [0,400), b1 [400,416), w2 [416,13216),
// b2 [13216,13248), w3 [13248,18368), b3 [18368,18378)

typedef __attribute__((ext_vector_type(8))) short short8;
typedef __attribute__((ext_vector_type(4))) float float4v;
typedef __attribute__((ext_vector_type(16))) float float16;

__device__ __forceinline__ unsigned short f2bf(float f) {
    union { float f; unsigned u; } v; v.f = f;
    unsigned r = v.u + 0x7fffu + ((v.u >> 16) & 1u);
    return (unsigned short)(r >> 16);
}
__device__ __forceinline__ float bf2f(unsigned short h) {
    union { unsigned u; float f; } v; v.u = ((unsigned)h) << 16;
    return v.f;
}

// ---------------- Kernel 1 (front): conv1 GEMM w/ inline im2col + weight prep ----------------
// blocks 0..511: (img, init-group) conv1 as K=32 MFMA GEMM, pool in-register.
// blocks 512..575: init i=blk-512: w2 -> wswz[init][tap][co32][cin16] bf16,
//                  w3 -> w3bf[init][o10][f512] bf16.
#define B_ROW 40   // im2col LDS row stride (elems)
__global__ __launch_bounds__(256) void front_kernel(
        const float* __restrict__ params,
        const float* __restrict__ batch,
        unsigned short* __restrict__ wswz,     // [init][25*32*16] bf16
        unsigned short* __restrict__ w3bf,     // [init][10*512] bf16
        unsigned short* __restrict__ act1) {   // [pair][144 pix][16 cin] bf16
    __shared__ unsigned short blds[576 * B_ROW];   // 46080 B (im2col)
    __shared__ unsigned short alds[16 * 512];      // 16384 B (w1, 16 inits)
    __shared__ float img[784];                     // 3136 B
    int blk = blockIdx.x;
    int t = threadIdx.x;

    if (blk >= 512) {   // weight prep path
        int i = blk - 512;
        const float* w2 = params + (size_t)i * P_TOTAL + 416;   // [co32][cin16][5][5]
        unsigned short* dst = wswz + (size_t)i * 12800;
        for (int k = t; k < 12800; k += 256) {
            int co = k / 400;
            int r = k - co * 400;
            int cin = r / 25;
            int s = r - cin * 25;   // s = ky*5+kx
            dst[(s * 32 + co) * 16 + cin] = f2bf(w2[k]);
        }
        const float* w3 = params + (size_t)i * P_TOTAL + 13248;
        unsigned short* d3 = w3bf + (size_t)i * 5120;
        for (int k = t; k < 5120; k += 256) d3[k] = f2bf(w3[k]);
        return;
    }

    int j  = blk >> 2;       // image
    int ig = blk & 3;        // init group (16 inits)

    { // phase 1: load image + convert w1 -> alds
        const float* ip = batch + j * 784;
        for (int k = t; k < 784; k += 256) img[k] = ip[k];
        for (int e = t; e < 8192; e += 256) {
            int il = e >> 9, r = e & 511;
            int m = r >> 5, k = r & 31;
            int init = ig * 16 + il;
            alds[il * 512 + m * 32 + k] =
                (k < 25) ? f2bf(params[(size_t)init * P_TOTAL + m * 25 + k]) : (unsigned short)0;
        }
    }
    __syncthreads();
    // phase 2: im2col img (LDS) -> blds. c = pp*4+q, k = ky*5+kx (zeros 25..31).
    for (int task = t; task < 2304; task += 256) {
        int c = task >> 2, kh = task & 3;
        int pp = c >> 2, q = c & 3;
        int py = pp / 12, px = pp - py * 12;
        int y0 = 2 * py + (q >> 1);
        int x0 = 2 * px + (q & 1);
        unsigned short ov[8] __attribute__((aligned(16)));
#pragma unroll
        for (int u = 0; u < 8; ++u) {
            int k = kh * 8 + u;
            float v = 0.f;
            if (k < 25) {
                int ky = k / 5, kx = k - ky * 5;
                v = img[(y0 + ky) * 28 + x0 + kx];
            }
            ov[u] = f2bf(v);
        }
        *(uint4*)(blds + c * B_ROW + kh * 8) = *(const uint4*)ov;
    }
    __syncthreads();

    int w = t >> 6, lane = t & 63;
    int co = lane & 15;
    int h = lane >> 4;

    short8 wfr[4];
    float bias[4];
    unsigned short* obase[4];
#pragma unroll
    for (int mt = 0; mt < 4; ++mt) {
        int il = w * 4 + mt;
        int init = ig * 16 + il;
        wfr[mt] = *(const short8*)(alds + il * 512 + co * 32 + h * 8);
        bias[mt] = params[(size_t)init * P_TOTAL + 400 + co];
        obase[mt] = act1 + ((size_t)(init * 128 + j) * 144 + h) * 16 + co;
    }

#pragma unroll 4
    for (int nt = 0; nt < 36; ++nt) {
        short8 afr = *(const short8*)(blds + (nt * 16 + co) * B_ROW + h * 8);
#pragma unroll
        for (int mt = 0; mt < 4; ++mt) {
            float4v acc = {0.f, 0.f, 0.f, 0.f};
            acc = __builtin_amdgcn_mfma_f32_16x16x32_bf16(afr, wfr[mt], acc, 0, 0, 0);
            float v = fmaxf(fmaxf(acc[0], acc[1]), fmaxf(acc[2], acc[3]));
            v = fmaxf(v + bias[mt], 0.f);
            obase[mt][(size_t)nt * 64] = f2bf(v);   // pix = nt*4+h
        }
    }
}

// ---------------- Kernel 2 (tail): conv2 MFMA + pool + dense + log_softmax ----------------
// Block = (init, 4-image group), 4 waves, wave w = image w. BARRIER-FREE:
//  - weights (wswz, w3bf) read straight from global (L2-resident: 1.6 + 0.65 MB total)
//  - each wave stages its own image into its own a1s slice (same-wave DS ordering)
//  - pool scratch aliases the wave's own a1s slice after MFMA (program order)
// LDS = 27,648 B -> ~5 blocks/CU (20 waves) vs R5's 2.
#define A1_PIX_STRIDE 24        // elems (48 B); 16B-aligned b128, ~4-way banks
#define IMG_LDS (144 * A1_PIX_STRIDE)   // 3456 elems = 6912 B per image
__global__ __launch_bounds__(256, 5) void tail_kernel(
        const float* __restrict__ params,
        const unsigned short* __restrict__ act1,   // [pair][144][16] bf16
        const unsigned short* __restrict__ wswz,   // [init][25][32][16] bf16
        const unsigned short* __restrict__ w3bf,   // [init][10][512] bf16
        float* __restrict__ out) {                 // [init][img][10] f32
    __shared__ unsigned short a1s[4 * IMG_LDS];    // 27648 B
    int b = blockIdx.x;
    int i = b >> 5;           // init
    int g = b & 31;           // image group
    int t = threadIdx.x;
    int w = t >> 6;           // wave = image index within group
    int lane = t & 63;
    int j = g * 4 + w;

    { // wave-private staging of image j (288 x 16B chunks, 4-5 per lane)
        const uint4* src = (const uint4*)(act1 + ((size_t)(i * 128 + j)) * 2304);
        unsigned short* dst0 = a1s + w * IMG_LDS;
        for (int c = lane; c < 288; c += 64) {
            int pix = c >> 1, h2 = c & 1;
            *(uint4*)(dst0 + pix * A1_PIX_STRIDE + h2 * 8) = src[c];
        }
    }
    // no barrier: this wave reads only its own writes

    int n = lane & 31;
    int h = lane >> 5;
    // A-fragments straight from global (coalesced 1KB/wave/tap, L2-hit)
    const short8* wg = (const short8*)(wswz + (size_t)i * 12800 + n * 16 + h * 8);
    int y0 = n >> 3, x0 = n & 7;
    const unsigned short* bbase = a1s + w * IMG_LDS;
    const short8* bptr0 = (const short8*)(bbase + ((y0    ) * 12 + x0) * A1_PIX_STRIDE + h * 8);
    const short8* bptr1 = (const short8*)(bbase + ((y0 + 4) * 12 + x0) * A1_PIX_STRIDE + h * 8);

    float16 acc0 = {};
    float16 acc1 = {};
#pragma unroll
    for (int ky = 0; ky < 5; ++ky) {
#pragma unroll
        for (int kx = 0; kx < 5; ++kx) {
            int tap = ky * 5 + kx;
            short8 af = wg[tap * 64];               // +tap*1024 B (global)
            int bo = (ky * 12 + kx) * 3;
            short8 b0 = bptr0[bo];
            short8 b1 = bptr1[bo];
            acc0 = __builtin_amdgcn_mfma_f32_32x32x16_bf16(af, b0, acc0, 0, 0, 0);
            acc1 = __builtin_amdgcn_mfma_f32_32x32x16_bf16(af, b1, acc1, 0, 0, 0);
        }
    }

    // two-phase pool using this wave's own a1s slice as f32 scratch (stride-33 pad)
    float* sw = (float*)(a1s + w * IMG_LDS);       // 6912 B >= 33*32*4 = 4224 B
    int co2 = lane >> 1;
    int half = lane & 1;      // 0: pooled rows 0-1 (tile0) ; 1: rows 2-3 (tile1)
    float bias2 = params[(size_t)i * P_TOTAL + 13216 + co2];
    float xr[8];

#pragma unroll
    for (int r = 0; r < 16; ++r) {                 // spill tile0
        int co = (r & 3) + 8 * (r >> 2) + 4 * h;
        sw[co * 33 + n] = acc0[r];
    }
    if (half == 0) {
#pragma unroll
        for (int it = 0; it < 8; ++it) {           // pp = it (py 0,1)
            int py = it >> 2, px = it & 3;
            const float* s = sw + co2 * 33 + (py * 2) * 8 + px * 2;
            float v = fmaxf(fmaxf(s[0], s[1]), fmaxf(s[8], s[9]));
            xr[it] = fmaxf(v + bias2, 0.f);
        }
    }
#pragma unroll
    for (int r = 0; r < 16; ++r) {                 // spill tile1 (after even-lane reads)
        int co = (r & 3) + 8 * (r >> 2) + 4 * h;
        sw[co * 33 + n] = acc1[r];
    }
    if (half == 1) {
#pragma unroll
        for (int it = 0; it < 8; ++it) {           // pp = 8+it (py 2,3 -> local rows 0,1)
            int pyl = it >> 2, px = it & 3;
            const float* s = sw + co2 * 33 + (pyl * 2) * 8 + px * 2;
            float v = fmaxf(fmaxf(s[0], s[1]), fmaxf(s[8], s[9]));
            xr[it] = fmaxf(v + bias2, 0.f);
        }
    }
    // lane L now holds features f = L*8 .. L*8+7 of image j

    // dense (10x512) + log_softmax; w3 bf16 from global (L2-resident)
    const unsigned short* w3p = w3bf + (size_t)i * 5120 + lane * 8;
    float acc[10];
#pragma unroll
    for (int o = 0; o < 10; ++o) {
        uint4 u = *(const uint4*)(w3p + o * 512);
        float a = 0.f;
        a = fmaf(xr[0], bf2f((unsigned short)(u.x & 0xffffu)), a);
        a = fmaf(xr[1], bf2f((unsigned short)(u.x >> 16)), a);
        a = fmaf(xr[2], bf2f((unsigned short)(u.y & 0xffffu)), a);
        a = fmaf(xr[3], bf2f((unsigned short)(u.y >> 16)), a);
        a = fmaf(xr[4], bf2f((unsigned short)(u.z & 0xffffu)), a);
        a = fmaf(xr[5], bf2f((unsigned short)(u.z >> 16)), a);
        a = fmaf(xr[6], bf2f((unsigned short)(u.w & 0xffffu)), a);
        a = fmaf(xr[7], bf2f((unsigned short)(u.w >> 16)), a);
#pragma unroll
        for (int d = 32; d >= 1; d >>= 1) a += __shfl_xor(a, d, 64);
        acc[o] = a;
    }
    const float* bp = params + (size_t)i * P_TOTAL + 18368;
    float m = -3.4e38f;
#pragma unroll
    for (int o = 0; o < 10; ++o) { acc[o] += bp[o]; m = fmaxf(m, acc[o]); }
    float ssum = 0.f;
#pragma unroll
    for (int o = 0; o < 10; ++o) ssum += expf(acc[o] - m);
    float ls = logf(ssum) + m;
    if (lane == 0) {
        float* op = out + ((size_t)i * 128 + j) * 10;
#pragma unroll
        for (int o = 0; o < 10; ++o) op[o] = acc[o] - ls;
    }
}

extern "C" void kernel_launch(void* const* d_in, const int* in_sizes, int n_in,
                              void* d_out, int out_size, void* d_ws, size_t ws_size,
                              hipStream_t stream) {
    const float* params = (const float*)d_in[0];   // (64, 18378) fp32
    const float* batch  = (const float*)d_in[1];   // (128, 1, 28, 28) fp32
    float* out = (float*)d_out;                    // (64, 128, 10) fp32

    // workspace: act1 37,748,736 B ; wswz 1,638,400 B ; w3bf 655,360 B
    unsigned short* act1 = (unsigned short*)d_ws;
    unsigned short* wswz = act1 + (size_t)64 * 128 * 2304;
    unsigned short* w3bf = wswz + (size_t)64 * 12800;

    front_kernel<<<576, 256, 0, stream>>>(params, batch, wswz, w3bf, act1);
    tail_kernel<<<2048, 256, 0, stream>>>(params, act1, wswz, w3bf, out);
}

// Round 7
// 114.861 us; speedup vs baseline: 1.2704x; 1.0418x over previous
//
#include <hip/hip_runtime.h>
#include <hip/hip_bf16.h>
#include <math.h>

// Problem constants
#define P_TOTAL 18378
// param breakpoints (floats): w1 [0,400), b1 [400,416), w2 [416,13216),
// b2 [13216,13248), w3 [13248,18368), b3 [18368,18378)

typedef __attribute__((ext_vector_type(8))) short short8;
typedef __attribute__((ext_vector_type(4))) float float4v;
typedef __attribute__((ext_vector_type(16))) float float16;

__device__ __forceinline__ unsigned short f2bf(float f) {
    union { float f; unsigned u; } v; v.f = f;
    unsigned r = v.u + 0x7fffu + ((v.u >> 16) & 1u);
    return (unsigned short)(r >> 16);
}
__device__ __forceinline__ float bf2f(unsigned short h) {
    union { unsigned u; float f; } v; v.u = ((unsigned)h) << 16;
    return v.f;
}

// ---------------- Kernel 0: prep ----------------
// blk 0..63 (init i): w2 -> wswz[i][tap][co32][cin16], w3 -> w3bf[i][10][512],
//                     w1 -> Amat[i][co16][32pad]  (all bf16)
// blk 64..191 (img j=blk-64): im2col -> Bmat[j][576 c][32 k] bf16,
//                     c = pp*4+q, pp = py*12+px, q = dy*2+dx, k = ky*5+kx.
__global__ __launch_bounds__(256) void prep_kernel(
        const float* __restrict__ params,
        const float* __restrict__ batch,
        unsigned short* __restrict__ wswz,
        unsigned short* __restrict__ w3bf,
        unsigned short* __restrict__ Amat,
        unsigned short* __restrict__ Bmat) {
    int blk = blockIdx.x;
    int t = threadIdx.x;
    if (blk < 64) {
        int i = blk;
        const float* w2 = params + (size_t)i * P_TOTAL + 416;   // [co32][cin16][5][5]
        unsigned short* dst = wswz + (size_t)i * 12800;
        for (int k = t; k < 12800; k += 256) {
            int co = k / 400;
            int r = k - co * 400;
            int cin = r / 25;
            int s = r - cin * 25;   // s = ky*5+kx
            dst[(s * 32 + co) * 16 + cin] = f2bf(w2[k]);
        }
        const float* w3 = params + (size_t)i * P_TOTAL + 13248;
        unsigned short* d3 = w3bf + (size_t)i * 5120;
        for (int k = t; k < 5120; k += 256) d3[k] = f2bf(w3[k]);
        const float* w1 = params + (size_t)i * P_TOTAL;          // [co16][25]
        unsigned short* d1 = Amat + (size_t)i * 512;
        for (int e = t; e < 512; e += 256) {
            int m = e >> 5, k = e & 31;
            d1[e] = (k < 25) ? f2bf(w1[m * 25 + k]) : (unsigned short)0;
        }
    } else {
        __shared__ float img[784];
        int j = blk - 64;
        const float* ip = batch + j * 784;
        for (int k = t; k < 784; k += 256) img[k] = ip[k];
        __syncthreads();
        unsigned short* dst = Bmat + (size_t)j * 18432;
        for (int task = t; task < 2304; task += 256) {
            int c = task >> 2, kh = task & 3;
            int pp = c >> 2, q = c & 3;
            int py = pp / 12, px = pp - py * 12;
            int y0 = 2 * py + (q >> 1);
            int x0 = 2 * px + (q & 1);
            unsigned short ov[8] __attribute__((aligned(16)));
#pragma unroll
            for (int u = 0; u < 8; ++u) {
                int k = kh * 8 + u;
                float v = 0.f;
                if (k < 25) {
                    int ky = k / 5, kx = k - ky * 5;
                    v = img[(y0 + ky) * 28 + x0 + kx];
                }
                ov[u] = f2bf(v);
            }
            *(uint4*)(dst + c * 32 + kh * 8) = *(const uint4*)ov;
        }
    }
}

// ---------------- Kernel 1: conv1 K=32 MFMA GEMM, no LDS, no barriers ----------------
// Grid = 128 img x 4 ig x 2 nt-halves = 1024 blocks, 256 thr; wave w -> 4 inits.
// A = im2col pixel rows (from global Bmat, wave-coalesced 1KB), B = w1 (from Amat).
// D: col=lane&15=co, row=(lane>>4)*4+reg = quad pixels of pp=nt*4+(lane>>4):
// pooling = 3 in-register fmax, store 2B/lane (128B/wave contiguous).
__global__ __launch_bounds__(256) void conv1_kernel(
        const float* __restrict__ params,
        const unsigned short* __restrict__ Amat,   // [64 init][16 co][32 k]
        const unsigned short* __restrict__ Bmat,   // [img][576 c][32 k]
        unsigned short* __restrict__ act1) {       // [pair][144 pix][16 cin]
    int blk = blockIdx.x;
    int s2 = blk & 1;        // nt half (0: nt 0..17, 1: nt 18..35)
    int ig = (blk >> 1) & 3; // init group (16 inits)
    int j  = blk >> 3;       // image
    int t = threadIdx.x;
    int w = t >> 6, lane = t & 63;
    int co = lane & 15;
    int h = lane >> 4;

    short8 wfr[4];
    float bias[4];
    unsigned short* obase[4];
#pragma unroll
    for (int mt = 0; mt < 4; ++mt) {
        int il = w * 4 + mt;
        int init = ig * 16 + il;
        wfr[mt] = *(const short8*)(Amat + (size_t)init * 512 + co * 32 + h * 8);
        bias[mt] = params[(size_t)init * P_TOTAL + 400 + co];
        obase[mt] = act1 + ((size_t)(init * 128 + j) * 144 + s2 * 72 + h) * 16 + co;
    }
    const unsigned short* bsrc = Bmat + (size_t)j * 18432 + (size_t)s2 * 18 * 16 * 32;

#pragma unroll 6
    for (int nt = 0; nt < 18; ++nt) {
        short8 afr = *(const short8*)(bsrc + (nt * 16 + co) * 32 + h * 8);
#pragma unroll
        for (int mt = 0; mt < 4; ++mt) {
            float4v acc = {0.f, 0.f, 0.f, 0.f};
            acc = __builtin_amdgcn_mfma_f32_16x16x32_bf16(afr, wfr[mt], acc, 0, 0, 0);
            float v = fmaxf(fmaxf(acc[0], acc[1]), fmaxf(acc[2], acc[3]));
            v = fmaxf(v + bias[mt], 0.f);
            obase[mt][(size_t)nt * 64] = f2bf(v);   // pix = s2*72 + nt*4 + h
        }
    }
}

// ---------------- Kernel 2 (tail): conv2 MFMA + pool + dense + log_softmax ----------------
// Block = (init, 4-image group), 4 waves, wave w = image w. BARRIER-FREE (R6).
#define A1_PIX_STRIDE 24        // elems (48 B)
#define IMG_LDS (144 * A1_PIX_STRIDE)   // 3456 elems = 6912 B per image
__global__ __launch_bounds__(256, 5) void tail_kernel(
        const float* __restrict__ params,
        const unsigned short* __restrict__ act1,   // [pair][144][16] bf16
        const unsigned short* __restrict__ wswz,   // [init][25][32][16] bf16
        const unsigned short* __restrict__ w3bf,   // [init][10][512] bf16
        float* __restrict__ out) {                 // [init][img][10] f32
    __shared__ unsigned short a1s[4 * IMG_LDS];    // 27648 B
    int b = blockIdx.x;
    int i = b >> 5;           // init
    int g = b & 31;           // image group
    int t = threadIdx.x;
    int w = t >> 6;           // wave = image index within group
    int lane = t & 63;
    int j = g * 4 + w;

    { // wave-private staging of image j
        const uint4* src = (const uint4*)(act1 + ((size_t)(i * 128 + j)) * 2304);
        unsigned short* dst0 = a1s + w * IMG_LDS;
        for (int c = lane; c < 288; c += 64) {
            int pix = c >> 1, h2 = c & 1;
            *(uint4*)(dst0 + pix * A1_PIX_STRIDE + h2 * 8) = src[c];
        }
    }
    // no barrier: this wave reads only its own writes

    int n = lane & 31;
    int h = lane >> 5;
    const short8* wg = (const short8*)(wswz + (size_t)i * 12800 + n * 16 + h * 8);
    int y0 = n >> 3, x0 = n & 7;
    const unsigned short* bbase = a1s + w * IMG_LDS;
    const short8* bptr0 = (const short8*)(bbase + ((y0    ) * 12 + x0) * A1_PIX_STRIDE + h * 8);
    const short8* bptr1 = (const short8*)(bbase + ((y0 + 4) * 12 + x0) * A1_PIX_STRIDE + h * 8);

    float16 acc0 = {};
    float16 acc1 = {};
#pragma unroll
    for (int ky = 0; ky < 5; ++ky) {
#pragma unroll
        for (int kx = 0; kx < 5; ++kx) {
            int tap = ky * 5 + kx;
            short8 af = wg[tap * 64];               // +tap*1024 B (global, L2)
            int bo = (ky * 12 + kx) * 3;
            short8 b0 = bptr0[bo];
            short8 b1 = bptr1[bo];
            acc0 = __builtin_amdgcn_mfma_f32_32x32x16_bf16(af, b0, acc0, 0, 0, 0);
            acc1 = __builtin_amdgcn_mfma_f32_32x32x16_bf16(af, b1, acc1, 0, 0, 0);
        }
    }

    // two-phase pool using this wave's own a1s slice as f32 scratch (stride-33 pad)
    float* sw = (float*)(a1s + w * IMG_LDS);
    int co2 = lane >> 1;
    int half = lane & 1;
    float bias2 = params[(size_t)i * P_TOTAL + 13216 + co2];
    float xr[8];

#pragma unroll
    for (int r = 0; r < 16; ++r) {                 // spill tile0
        int co = (r & 3) + 8 * (r >> 2) + 4 * h;
        sw[co * 33 + n] = acc0[r];
    }
    if (half == 0) {
#pragma unroll
        for (int it = 0; it < 8; ++it) {
            int py = it >> 2, px = it & 3;
            const float* s = sw + co2 * 33 + (py * 2) * 8 + px * 2;
            float v = fmaxf(fmaxf(s[0], s[1]), fmaxf(s[8], s[9]));
            xr[it] = fmaxf(v + bias2, 0.f);
        }
    }
#pragma unroll
    for (int r = 0; r < 16; ++r) {                 // spill tile1
        int co = (r & 3) + 8 * (r >> 2) + 4 * h;
        sw[co * 33 + n] = acc1[r];
    }
    if (half == 1) {
#pragma unroll
        for (int it = 0; it < 8; ++it) {
            int pyl = it >> 2, px = it & 3;
            const float* s = sw + co2 * 33 + (pyl * 2) * 8 + px * 2;
            float v = fmaxf(fmaxf(s[0], s[1]), fmaxf(s[8], s[9]));
            xr[it] = fmaxf(v + bias2, 0.f);
        }
    }
    // lane L holds features f = L*8 .. L*8+7 of image j

    const unsigned short* w3p = w3bf + (size_t)i * 5120 + lane * 8;
    float acc[10];
#pragma unroll
    for (int o = 0; o < 10; ++o) {
        uint4 u = *(const uint4*)(w3p + o * 512);
        float a = 0.f;
        a = fmaf(xr[0], bf2f((unsigned short)(u.x & 0xffffu)), a);
        a = fmaf(xr[1], bf2f((unsigned short)(u.x >> 16)), a);
        a = fmaf(xr[2], bf2f((unsigned short)(u.y & 0xffffu)), a);
        a = fmaf(xr[3], bf2f((unsigned short)(u.y >> 16)), a);
        a = fmaf(xr[4], bf2f((unsigned short)(u.z & 0xffffu)), a);
        a = fmaf(xr[5], bf2f((unsigned short)(u.z >> 16)), a);
        a = fmaf(xr[6], bf2f((unsigned short)(u.w & 0xffffu)), a);
        a = fmaf(xr[7], bf2f((unsigned short)(u.w >> 16)), a);
#pragma unroll
        for (int d = 32; d >= 1; d >>= 1) a += __shfl_xor(a, d, 64);
        acc[o] = a;
    }
    const float* bp = params + (size_t)i * P_TOTAL + 18368;
    float m = -3.4e38f;
#pragma unroll
    for (int o = 0; o < 10; ++o) { acc[o] += bp[o]; m = fmaxf(m, acc[o]); }
    float ssum = 0.f;
#pragma unroll
    for (int o = 0; o < 10; ++o) ssum += expf(acc[o] - m);
    float ls = logf(ssum) + m;
    if (lane == 0) {
        float* op = out + ((size_t)i * 128 + j) * 10;
#pragma unroll
        for (int o = 0; o < 10; ++o) op[o] = acc[o] - ls;
    }
}

extern "C" void kernel_launch(void* const* d_in, const int* in_sizes, int n_in,
                              void* d_out, int out_size, void* d_ws, size_t ws_size,
                              hipStream_t stream) {
    const float* params = (const float*)d_in[0];   // (64, 18378) fp32
    const float* batch  = (const float*)d_in[1];   // (128, 1, 28, 28) fp32
    float* out = (float*)d_out;                    // (64, 128, 10) fp32

    // workspace: act1 37,748,736 B ; wswz 1,638,400 B ; w3bf 655,360 B ;
    //            Amat 65,536 B ; Bmat 4,718,592 B
    unsigned short* act1 = (unsigned short*)d_ws;
    unsigned short* wswz = act1 + (size_t)64 * 128 * 2304;
    unsigned short* w3bf = wswz + (size_t)64 * 12800;
    unsigned short* Amat = w3bf + (size_t)64 * 5120;
    unsigned short* Bmat = Amat + (size_t)64 * 512;

    prep_kernel<<<192, 256, 0, stream>>>(params, batch, wswz, w3bf, Amat, Bmat);
    conv1_kernel<<<1024, 256, 0, stream>>>(params, Amat, Bmat, act1);
    tail_kernel<<<2048, 256, 0, stream>>>(params, act1, wswz, w3bf, out);
}

// Round 8
// 107.838 us; speedup vs baseline: 1.3531x; 1.0651x over previous
//
#include <hip/hip_runtime.h>
#include <hip/hip_bf16.h>
#include <math.h>

// Problem constants
#define P_TOTAL 18378
// param breakpoints (floats): w1 [0,400), b1 [400,416), w2 [416,13216),
// b2 [13216,13248), w3 [13248,18368), b3 [18368,18378)

typedef __attribute__((ext_vector_type(8))) short short8;
typedef __attribute__((ext_vector_type(4))) float float4v;
typedef __attribute__((ext_vector_type(16))) float float16;

__device__ __forceinline__ unsigned short f2bf(float f) {
    union { float f; unsigned u; } v; v.f = f;
    unsigned r = v.u + 0x7fffu + ((v.u >> 16) & 1u);
    return (unsigned short)(r >> 16);
}
__device__ __forceinline__ float bf2f(unsigned short h) {
    union { unsigned u; float f; } v; v.u = ((unsigned)h) << 16;
    return v.f;
}

// ---------------- Kernel 0: prep ----------------
// blk 0..63 (init i): w2 -> wswz[i][tap][co32][cin16], w3 -> w3bf[i][10][512],
//                     w1 -> w1bf[i][co16][32pad]  (all bf16)
// blk 64..191 (img j=blk-64): im2col -> Bmat[j][576 c][32 k] bf16,
//                     c = pp*4+q, pp = py*12+px, q = dy*2+dx, k = ky*5+kx.
__global__ __launch_bounds__(256) void prep_kernel(
        const float* __restrict__ params,
        const float* __restrict__ batch,
        unsigned short* __restrict__ wswz,
        unsigned short* __restrict__ w3bf,
        unsigned short* __restrict__ w1bf,
        unsigned short* __restrict__ Bmat) {
    int blk = blockIdx.x;
    int t = threadIdx.x;
    if (blk < 64) {
        int i = blk;
        const float* w2 = params + (size_t)i * P_TOTAL + 416;   // [co32][cin16][5][5]
        unsigned short* dst = wswz + (size_t)i * 12800;
        for (int k = t; k < 12800; k += 256) {
            int co = k / 400;
            int r = k - co * 400;
            int cin = r / 25;
            int s = r - cin * 25;   // s = ky*5+kx
            dst[(s * 32 + co) * 16 + cin] = f2bf(w2[k]);
        }
        const float* w3 = params + (size_t)i * P_TOTAL + 13248;
        unsigned short* d3 = w3bf + (size_t)i * 5120;
        for (int k = t; k < 5120; k += 256) d3[k] = f2bf(w3[k]);
        const float* w1 = params + (size_t)i * P_TOTAL;          // [co16][25]
        unsigned short* d1 = w1bf + (size_t)i * 512;
        for (int e = t; e < 512; e += 256) {
            int m = e >> 5, k = e & 31;
            d1[e] = (k < 25) ? f2bf(w1[m * 25 + k]) : (unsigned short)0;
        }
    } else {
        __shared__ float img[784];
        int j = blk - 64;
        const float* ip = batch + j * 784;
        for (int k = t; k < 784; k += 256) img[k] = ip[k];
        __syncthreads();
        unsigned short* dst = Bmat + (size_t)j * 18432;
        for (int task = t; task < 2304; task += 256) {
            int c = task >> 2, kh = task & 3;
            int pp = c >> 2, q = c & 3;
            int py = pp / 12, px = pp - py * 12;
            int y0 = 2 * py + (q >> 1);
            int x0 = 2 * px + (q & 1);
            unsigned short ov[8] __attribute__((aligned(16)));
#pragma unroll
            for (int u = 0; u < 8; ++u) {
                int k = kh * 8 + u;
                float v = 0.f;
                if (k < 25) {
                    int ky = k / 5, kx = k - ky * 5;
                    v = img[(y0 + ky) * 28 + x0 + kx];
                }
                ov[u] = f2bf(v);
            }
            *(uint4*)(dst + c * 32 + kh * 8) = *(const uint4*)ov;
        }
    }
}

// ---------------- Kernel 1 (mega): conv1 + conv2 + pool + dense + log_softmax ----------------
// Block = (init i, image-group g of 4), 4 waves, wave w = image j = g*4+w.
// BARRIER-FREE: every LDS byte a wave touches is its own slice; all weight
// operands come from global (L2/L3-resident); chain is same-wave program order.
// Phase A (conv1): 36 x mfma_16x16x32 (A=im2col rows from Bmat, B=w1bf),
//   pool in-register (D rows = quad pixels), ds_write_b16 pooled bf16 into
//   this wave's a1s slice in [pix][cin] / A1_PIX_STRIDE layout.
// Phase B (conv2): 25 taps x 2 x mfma_32x32x16 from a1s + wswz (global).
// Phase C: two-phase pool via f32 scratch aliasing own slice; dense + lsm.
#define A1_PIX_STRIDE 24        // elems (48 B)
#define IMG_LDS (144 * A1_PIX_STRIDE)   // 3456 elems = 6912 B per image
__global__ __launch_bounds__(256, 5) void mega_kernel(
        const float* __restrict__ params,
        const unsigned short* __restrict__ Bmat,   // [img][576][32] bf16 im2col
        const unsigned short* __restrict__ w1bf,   // [init][16][32] bf16
        const unsigned short* __restrict__ wswz,   // [init][25][32][16] bf16
        const unsigned short* __restrict__ w3bf,   // [init][10][512] bf16
        float* __restrict__ out) {                 // [init][img][10] f32
    __shared__ unsigned short a1s[4 * IMG_LDS];    // 27648 B
    int b = blockIdx.x;
    int i = b >> 5;           // init
    int g = b & 31;           // image group
    int t = threadIdx.x;
    int w = t >> 6;           // wave = image index within group
    int lane = t & 63;
    int j = g * 4 + w;

    // ---- Phase A: conv1 for (init i, image j), output -> own a1s slice ----
    {
        int co = lane & 15;       // conv1 out-channel = conv2 cin
        int h4 = lane >> 4;       // pool-quad row group
        short8 wfr = *(const short8*)(w1bf + (size_t)i * 512 + co * 32 + h4 * 8);
        float bias1 = params[(size_t)i * P_TOTAL + 400 + co];
        unsigned short* dst = a1s + w * IMG_LDS;
        const unsigned short* bsrc = Bmat + (size_t)j * 18432;
#pragma unroll 6
        for (int nt = 0; nt < 36; ++nt) {
            short8 afr = *(const short8*)(bsrc + (nt * 16 + co) * 32 + h4 * 8);
            float4v acc = {0.f, 0.f, 0.f, 0.f};
            acc = __builtin_amdgcn_mfma_f32_16x16x32_bf16(afr, wfr, acc, 0, 0, 0);
            float v = fmaxf(fmaxf(acc[0], acc[1]), fmaxf(acc[2], acc[3]));
            v = fmaxf(v + bias1, 0.f);
            dst[(nt * 4 + h4) * A1_PIX_STRIDE + co] = f2bf(v);   // pix = nt*4+h4
        }
    }
    // no barrier: this wave reads only its own writes (DS program order)

    // ---- Phase B: conv2 (25 taps x 2 tiles of mfma_32x32x16) ----
    int n = lane & 31;
    int h = lane >> 5;
    const short8* wg = (const short8*)(wswz + (size_t)i * 12800 + n * 16 + h * 8);
    int y0 = n >> 3, x0 = n & 7;
    const unsigned short* bbase = a1s + w * IMG_LDS;
    const short8* bptr0 = (const short8*)(bbase + ((y0    ) * 12 + x0) * A1_PIX_STRIDE + h * 8);
    const short8* bptr1 = (const short8*)(bbase + ((y0 + 4) * 12 + x0) * A1_PIX_STRIDE + h * 8);

    float16 acc0 = {};
    float16 acc1 = {};
#pragma unroll
    for (int ky = 0; ky < 5; ++ky) {
#pragma unroll
        for (int kx = 0; kx < 5; ++kx) {
            int tap = ky * 5 + kx;
            short8 af = wg[tap * 64];               // +tap*1024 B (global, L2)
            int bo = (ky * 12 + kx) * 3;
            short8 b0 = bptr0[bo];
            short8 b1 = bptr1[bo];
            acc0 = __builtin_amdgcn_mfma_f32_32x32x16_bf16(af, b0, acc0, 0, 0, 0);
            acc1 = __builtin_amdgcn_mfma_f32_32x32x16_bf16(af, b1, acc1, 0, 0, 0);
        }
    }

    // ---- Phase C: pool (scratch aliases own slice) + dense + log_softmax ----
    float* sw = (float*)(a1s + w * IMG_LDS);       // 6912 B >= 33*32*4 = 4224 B
    int co2 = lane >> 1;
    int half = lane & 1;
    float bias2 = params[(size_t)i * P_TOTAL + 13216 + co2];
    float xr[8];

#pragma unroll
    for (int r = 0; r < 16; ++r) {                 // spill tile0
        int co = (r & 3) + 8 * (r >> 2) + 4 * h;
        sw[co * 33 + n] = acc0[r];
    }
    if (half == 0) {
#pragma unroll
        for (int it = 0; it < 8; ++it) {           // pp = it (py 0,1)
            int py = it >> 2, px = it & 3;
            const float* s = sw + co2 * 33 + (py * 2) * 8 + px * 2;
            float v = fmaxf(fmaxf(s[0], s[1]), fmaxf(s[8], s[9]));
            xr[it] = fmaxf(v + bias2, 0.f);
        }
    }
#pragma unroll
    for (int r = 0; r < 16; ++r) {                 // spill tile1
        int co = (r & 3) + 8 * (r >> 2) + 4 * h;
        sw[co * 33 + n] = acc1[r];
    }
    if (half == 1) {
#pragma unroll
        for (int it = 0; it < 8; ++it) {           // pp = 8+it (py 2,3)
            int pyl = it >> 2, px = it & 3;
            const float* s = sw + co2 * 33 + (pyl * 2) * 8 + px * 2;
            float v = fmaxf(fmaxf(s[0], s[1]), fmaxf(s[8], s[9]));
            xr[it] = fmaxf(v + bias2, 0.f);
        }
    }
    // lane L holds features f = L*8 .. L*8+7 of image j

    const unsigned short* w3p = w3bf + (size_t)i * 5120 + lane * 8;
    float acc[10];
#pragma unroll
    for (int o = 0; o < 10; ++o) {
        uint4 u = *(const uint4*)(w3p + o * 512);
        float a = 0.f;
        a = fmaf(xr[0], bf2f((unsigned short)(u.x & 0xffffu)), a);
        a = fmaf(xr[1], bf2f((unsigned short)(u.x >> 16)), a);
        a = fmaf(xr[2], bf2f((unsigned short)(u.y & 0xffffu)), a);
        a = fmaf(xr[3], bf2f((unsigned short)(u.y >> 16)), a);
        a = fmaf(xr[4], bf2f((unsigned short)(u.z & 0xffffu)), a);
        a = fmaf(xr[5], bf2f((unsigned short)(u.z >> 16)), a);
        a = fmaf(xr[6], bf2f((unsigned short)(u.w & 0xffffu)), a);
        a = fmaf(xr[7], bf2f((unsigned short)(u.w >> 16)), a);
#pragma unroll
        for (int d = 32; d >= 1; d >>= 1) a += __shfl_xor(a, d, 64);
        acc[o] = a;
    }
    const float* bp = params + (size_t)i * P_TOTAL + 18368;
    float m = -3.4e38f;
#pragma unroll
    for (int o = 0; o < 10; ++o) { acc[o] += bp[o]; m = fmaxf(m, acc[o]); }
    float ssum = 0.f;
#pragma unroll
    for (int o = 0; o < 10; ++o) ssum += expf(acc[o] - m);
    float ls = logf(ssum) + m;
    if (lane == 0) {
        float* op = out + ((size_t)i * 128 + j) * 10;
#pragma unroll
        for (int o = 0; o < 10; ++o) op[o] = acc[o] - ls;
    }
}

extern "C" void kernel_launch(void* const* d_in, const int* in_sizes, int n_in,
                              void* d_out, int out_size, void* d_ws, size_t ws_size,
                              hipStream_t stream) {
    const float* params = (const float*)d_in[0];   // (64, 18378) fp32
    const float* batch  = (const float*)d_in[1];   // (128, 1, 28, 28) fp32
    float* out = (float*)d_out;                    // (64, 128, 10) fp32

    // workspace: wswz 1,638,400 B ; w3bf 655,360 B ; w1bf 65,536 B ; Bmat 4,718,592 B
    unsigned short* wswz = (unsigned short*)d_ws;
    unsigned short* w3bf = wswz + (size_t)64 * 12800;
    unsigned short* w1bf = w3bf + (size_t)64 * 5120;
    unsigned short* Bmat = w1bf + (size_t)64 * 512;

    prep_kernel<<<192, 256, 0, stream>>>(params, batch, wswz, w3bf, w1bf, Bmat);
    mega_kernel<<<2048, 256, 0, stream>>>(params, Bmat, w1bf, wswz, w3bf, out);
}

// Round 9
// 106.850 us; speedup vs baseline: 1.3657x; 1.0093x over previous
//
#include <hip/hip_runtime.h>
#include <hip/hip_bf16.h>
#include <math.h>

// Problem constants
#define P_TOTAL 18378
// param breakpoints (floats): w1 [0,400), b1 [400,416), w2 [416,13216),
// b2 [13216,13248), w3 [13248,18368), b3 [18368,18378)

typedef __attribute__((ext_vector_type(8))) short short8;
typedef __attribute__((ext_vector_type(4))) float float4v;
typedef __attribute__((ext_vector_type(16))) float float16;

__device__ __forceinline__ unsigned short f2bf(float f) {
    union { float f; unsigned u; } v; v.f = f;
    unsigned r = v.u + 0x7fffu + ((v.u >> 16) & 1u);
    return (unsigned short)(r >> 16);
}
__device__ __forceinline__ float bf2f(unsigned short h) {
    union { unsigned u; float f; } v; v.u = ((unsigned)h) << 16;
    return v.f;
}

// ---------------- Kernel 0: prep ----------------
// blk 0..63 (init i): w2 -> wswz[i][tap][co32][cin16], w1 -> w1bf[i][co16][32pad],
//   w3 -> w3l[i][o10][lane64][slot8] PERMUTED for mega's in-register pool layout:
//   lane l = h*32+co, slot s = py*2+d  ->  feature f = co*16 + py*4 + 2h + d.
// blk 64..191 (img j=blk-64): im2col -> Bmat[j][576 c][32 k] bf16,
//   c = pp*4+q, pp = py*12+px, q = dy*2+dx, k = ky*5+kx.
__global__ __launch_bounds__(256) void prep_kernel(
        const float* __restrict__ params,
        const float* __restrict__ batch,
        unsigned short* __restrict__ wswz,
        unsigned short* __restrict__ w3l,
        unsigned short* __restrict__ w1bf,
        unsigned short* __restrict__ Bmat) {
    int blk = blockIdx.x;
    int t = threadIdx.x;
    if (blk < 64) {
        int i = blk;
        const float* w2 = params + (size_t)i * P_TOTAL + 416;   // [co32][cin16][5][5]
        unsigned short* dst = wswz + (size_t)i * 12800;
        for (int k = t; k < 12800; k += 256) {
            int co = k / 400;
            int r = k - co * 400;
            int cin = r / 25;
            int s = r - cin * 25;   // s = ky*5+kx
            dst[(s * 32 + co) * 16 + cin] = f2bf(w2[k]);
        }
        const float* w3 = params + (size_t)i * P_TOTAL + 13248;  // [o10][f512]
        unsigned short* d3 = w3l + (size_t)i * 5120;
        for (int k = t; k < 5120; k += 256) {
            int o = k >> 9, r = k & 511;
            int l = r >> 3, s = r & 7;
            int co = l & 31, h = l >> 5;
            int py = s >> 1, d = s & 1;
            d3[k] = f2bf(w3[o * 512 + co * 16 + py * 4 + 2 * h + d]);
        }
        const float* w1 = params + (size_t)i * P_TOTAL;          // [co16][25]
        unsigned short* d1 = w1bf + (size_t)i * 512;
        for (int e = t; e < 512; e += 256) {
            int m = e >> 5, k = e & 31;
            d1[e] = (k < 25) ? f2bf(w1[m * 25 + k]) : (unsigned short)0;
        }
    } else {
        __shared__ float img[784];
        int j = blk - 64;
        const float* ip = batch + j * 784;
        for (int k = t; k < 784; k += 256) img[k] = ip[k];
        __syncthreads();
        unsigned short* dst = Bmat + (size_t)j * 18432;
        for (int task = t; task < 2304; task += 256) {
            int c = task >> 2, kh = task & 3;
            int pp = c >> 2, q = c & 3;
            int py = pp / 12, px = pp - py * 12;
            int y0 = 2 * py + (q >> 1);
            int x0 = 2 * px + (q & 1);
            unsigned short ov[8] __attribute__((aligned(16)));
#pragma unroll
            for (int u = 0; u < 8; ++u) {
                int k = kh * 8 + u;
                float v = 0.f;
                if (k < 25) {
                    int ky = k / 5, kx = k - ky * 5;
                    v = img[(y0 + ky) * 28 + x0 + kx];
                }
                ov[u] = f2bf(v);
            }
            *(uint4*)(dst + c * 32 + kh * 8) = *(const uint4*)ov;
        }
    }
}

// ---------------- Kernel 1 (mega): conv1 + conv2 + pool + dense + log_softmax ----------------
// Block = (init i, image-group g of 4), 4 waves, wave w = image j = g*4+w.
// BARRIER-FREE: every LDS byte a wave touches is its own slice; weights from
// global (L2-resident); same-wave DS program order covers phase A->B.
// Phase A (conv1): 36 x mfma_16x16x32, pool in-register, ds_write_b16 into
//   own a1s slice ([pix][cin], A1_PIX_STRIDE layout).
// Phase B (conv2): 25 taps x 2 x mfma_32x32x16, A = PIXELS (a1s), B = co (wswz).
//   D rows = pixels -> each lane's 16 regs contain four full 2x2 pool windows.
// Phase C: pool IN REGISTERS (no LDS, no shuffles, no divergence), then dense
//   with permuted w3l + wave shfl-reduction, log_softmax, store.
#define A1_PIX_STRIDE 24        // elems (48 B)
#define IMG_LDS (144 * A1_PIX_STRIDE)   // 3456 elems = 6912 B per image
__global__ __launch_bounds__(256, 5) void mega_kernel(
        const float* __restrict__ params,
        const unsigned short* __restrict__ Bmat,   // [img][576][32] bf16 im2col
        const unsigned short* __restrict__ w1bf,   // [init][16][32] bf16
        const unsigned short* __restrict__ wswz,   // [init][25][32][16] bf16
        const unsigned short* __restrict__ w3l,    // [init][10][64][8] bf16 (permuted)
        float* __restrict__ out) {                 // [init][img][10] f32
    __shared__ unsigned short a1s[4 * IMG_LDS];    // 27648 B
    int b = blockIdx.x;
    int i = b >> 5;           // init
    int g = b & 31;           // image group
    int t = threadIdx.x;
    int w = t >> 6;           // wave = image index within group
    int lane = t & 63;
    int j = g * 4 + w;

    // ---- Phase A: conv1 for (init i, image j), output -> own a1s slice ----
    {
        int co = lane & 15;       // conv1 out-channel = conv2 cin
        int h4 = lane >> 4;       // pool-quad row group
        short8 wfr = *(const short8*)(w1bf + (size_t)i * 512 + co * 32 + h4 * 8);
        float bias1 = params[(size_t)i * P_TOTAL + 400 + co];
        unsigned short* dst = a1s + w * IMG_LDS;
        const unsigned short* bsrc = Bmat + (size_t)j * 18432;
#pragma unroll 6
        for (int nt = 0; nt < 36; ++nt) {
            short8 afr = *(const short8*)(bsrc + (nt * 16 + co) * 32 + h4 * 8);
            float4v acc = {0.f, 0.f, 0.f, 0.f};
            acc = __builtin_amdgcn_mfma_f32_16x16x32_bf16(afr, wfr, acc, 0, 0, 0);
            float v = fmaxf(fmaxf(acc[0], acc[1]), fmaxf(acc[2], acc[3]));
            v = fmaxf(v + bias1, 0.f);
            dst[(nt * 4 + h4) * A1_PIX_STRIDE + co] = f2bf(v);   // pix = nt*4+h4
        }
    }
    // no barrier: this wave reads only its own writes (DS program order)

    // ---- Phase B: conv2, A = pixels (a1s), B = out-channels (wswz) ----
    int n = lane & 31;        // A row = pixel ; B col = co
    int h = lane >> 5;        // k-half
    const short8* wg = (const short8*)(wswz + (size_t)i * 12800 + n * 16 + h * 8);
    int y0 = n >> 3, x0 = n & 7;
    const unsigned short* bbase = a1s + w * IMG_LDS;
    const short8* pptr0 = (const short8*)(bbase + ((y0    ) * 12 + x0) * A1_PIX_STRIDE + h * 8);
    const short8* pptr1 = (const short8*)(bbase + ((y0 + 4) * 12 + x0) * A1_PIX_STRIDE + h * 8);

    float16 acc0 = {};   // D rows = pixels 0..31 (y 0..3), cols = co
    float16 acc1 = {};   // D rows = pixels 32..63 (y 4..7)
#pragma unroll
    for (int ky = 0; ky < 5; ++ky) {
#pragma unroll
        for (int kx = 0; kx < 5; ++kx) {
            int tap = ky * 5 + kx;
            short8 wf = wg[tap * 64];               // +tap*1024 B (global, L2)
            int bo = (ky * 12 + kx) * 3;
            short8 p0 = pptr0[bo];
            short8 p1 = pptr1[bo];
            acc0 = __builtin_amdgcn_mfma_f32_32x32x16_bf16(p0, wf, acc0, 0, 0, 0);
            acc1 = __builtin_amdgcn_mfma_f32_32x32x16_bf16(p1, wf, acc1, 0, 0, 0);
        }
    }

    // ---- Phase C: in-register 2x2 pool + bias + ReLU ----
    // row r = (reg&3) + 8*(reg>>2) + 4h  ->  pixel (y = p>>3, x = p&7).
    // pooled (pyl,d): regs {base, base+1, base+4, base+5}, base = pyl*8 + d*2.
    // lane (co = lane&31, h) ends with 8 features f = co*16 + py*4 + 2h + d,
    // slot s = py*2 + d  (py = tile*2 + pyl)  — matches w3l's prep permutation.
    int co2 = lane & 31;
    float bias2 = params[(size_t)i * P_TOTAL + 13216 + co2];
    float xr[8];
#pragma unroll
    for (int pyl = 0; pyl < 2; ++pyl) {
#pragma unroll
        for (int d = 0; d < 2; ++d) {
            int base = pyl * 8 + d * 2;
            float v0 = fmaxf(fmaxf(acc0[base], acc0[base + 1]),
                             fmaxf(acc0[base + 4], acc0[base + 5]));
            float v1 = fmaxf(fmaxf(acc1[base], acc1[base + 1]),
                             fmaxf(acc1[base + 4], acc1[base + 5]));
            xr[pyl * 2 + d]     = fmaxf(v0 + bias2, 0.f);   // py = pyl
            xr[4 + pyl * 2 + d] = fmaxf(v1 + bias2, 0.f);   // py = 2+pyl
        }
    }

    // ---- dense (10x512) + log_softmax; w3l permuted so this lane's 8 slots
    //      multiply its 8 features directly ----
    const unsigned short* w3p = w3l + (size_t)i * 5120 + lane * 8;
    float acc[10];
#pragma unroll
    for (int o = 0; o < 10; ++o) {
        uint4 u = *(const uint4*)(w3p + o * 512);
        float a = 0.f;
        a = fmaf(xr[0], bf2f((unsigned short)(u.x & 0xffffu)), a);
        a = fmaf(xr[1], bf2f((unsigned short)(u.x >> 16)), a);
        a = fmaf(xr[2], bf2f((unsigned short)(u.y & 0xffffu)), a);
        a = fmaf(xr[3], bf2f((unsigned short)(u.y >> 16)), a);
        a = fmaf(xr[4], bf2f((unsigned short)(u.z & 0xffffu)), a);
        a = fmaf(xr[5], bf2f((unsigned short)(u.z >> 16)), a);
        a = fmaf(xr[6], bf2f((unsigned short)(u.w & 0xffffu)), a);
        a = fmaf(xr[7], bf2f((unsigned short)(u.w >> 16)), a);
#pragma unroll
        for (int d = 32; d >= 1; d >>= 1) a += __shfl_xor(a, d, 64);
        acc[o] = a;
    }
    const float* bp = params + (size_t)i * P_TOTAL + 18368;
    float m = -3.4e38f;
#pragma unroll
    for (int o = 0; o < 10; ++o) { acc[o] += bp[o]; m = fmaxf(m, acc[o]); }
    float ssum = 0.f;
#pragma unroll
    for (int o = 0; o < 10; ++o) ssum += expf(acc[o] - m);
    float ls = logf(ssum) + m;
    if (lane == 0) {
        float* op = out + ((size_t)i * 128 + j) * 10;
#pragma unroll
        for (int o = 0; o < 10; ++o) op[o] = acc[o] - ls;
    }
}

extern "C" void kernel_launch(void* const* d_in, const int* in_sizes, int n_in,
                              void* d_out, int out_size, void* d_ws, size_t ws_size,
                              hipStream_t stream) {
    const float* params = (const float*)d_in[0];   // (64, 18378) fp32
    const float* batch  = (const float*)d_in[1];   // (128, 1, 28, 28) fp32
    float* out = (float*)d_out;                    // (64, 128, 10) fp32

    // workspace: wswz 1,638,400 B ; w3l 655,360 B ; w1bf 65,536 B ; Bmat 4,718,592 B
    unsigned short* wswz = (unsigned short*)d_ws;
    unsigned short* w3l  = wswz + (size_t)64 * 12800;
    unsigned short* w1bf = w3l + (size_t)64 * 5120;
    unsigned short* Bmat = w1bf + (size_t)64 * 512;

    prep_kernel<<<192, 256, 0, stream>>>(params, batch, wswz, w3l, w1bf, Bmat);
    mega_kernel<<<2048, 256, 0, stream>>>(params, Bmat, w1bf, wswz, w3l, out);
}

// Round 10
// 106.194 us; speedup vs baseline: 1.3741x; 1.0062x over previous
//
#include <hip/hip_runtime.h>
#include <hip/hip_bf16.h>
#include <math.h>

// Problem constants
#define P_TOTAL 18378
// param breakpoints (floats): w1 [0,400), b1 [400,416), w2 [416,13216),
// b2 [13216,13248), w3 [13248,18368), b3 [18368,18378)

typedef __attribute__((ext_vector_type(8))) short short8;
typedef __attribute__((ext_vector_type(4))) float float4v;
typedef __attribute__((ext_vector_type(16))) float float16;

__device__ __forceinline__ unsigned short f2bf(float f) {
    union { float f; unsigned u; } v; v.f = f;
    unsigned r = v.u + 0x7fffu + ((v.u >> 16) & 1u);
    return (unsigned short)(r >> 16);
}
__device__ __forceinline__ float bf2f(unsigned short h) {
    union { unsigned u; float f; } v; v.u = ((unsigned)h) << 16;
    return v.f;
}

// ---------------- Kernel 0: prep ----------------
// blk 0..63 (init i): w2 -> wswz[i][tap][co32][cin16], w1 -> w1bf[i][co16][32pad],
//   w3 -> w3l[i][o10][lane64][slot8] permuted for mega's in-register pool layout:
//   lane l = h*32+co, slot s = py*2+d  ->  feature f = co*16 + py*4 + 2h + d.
// blk 64..191 (img j=blk-64): im2col -> Bmat[j][576 c][32 k] bf16,
//   c = pp*4+q, pp = py*12+px, q = dy*2+dx, k = ky*5+kx.
__global__ __launch_bounds__(256) void prep_kernel(
        const float* __restrict__ params,
        const float* __restrict__ batch,
        unsigned short* __restrict__ wswz,
        unsigned short* __restrict__ w3l,
        unsigned short* __restrict__ w1bf,
        unsigned short* __restrict__ Bmat) {
    int blk = blockIdx.x;
    int t = threadIdx.x;
    if (blk < 64) {
        int i = blk;
        const float* w2 = params + (size_t)i * P_TOTAL + 416;   // [co32][cin16][5][5]
        unsigned short* dst = wswz + (size_t)i * 12800;
        for (int k = t; k < 12800; k += 256) {
            int co = k / 400;
            int r = k - co * 400;
            int cin = r / 25;
            int s = r - cin * 25;   // s = ky*5+kx
            dst[(s * 32 + co) * 16 + cin] = f2bf(w2[k]);
        }
        const float* w3 = params + (size_t)i * P_TOTAL + 13248;  // [o10][f512]
        unsigned short* d3 = w3l + (size_t)i * 5120;
        for (int k = t; k < 5120; k += 256) {
            int o = k >> 9, r = k & 511;
            int l = r >> 3, s = r & 7;
            int co = l & 31, h = l >> 5;
            int py = s >> 1, d = s & 1;
            d3[k] = f2bf(w3[o * 512 + co * 16 + py * 4 + 2 * h + d]);
        }
        const float* w1 = params + (size_t)i * P_TOTAL;          // [co16][25]
        unsigned short* d1 = w1bf + (size_t)i * 512;
        for (int e = t; e < 512; e += 256) {
            int m = e >> 5, k = e & 31;
            d1[e] = (k < 25) ? f2bf(w1[m * 25 + k]) : (unsigned short)0;
        }
    } else {
        __shared__ float img[784];
        int j = blk - 64;
        const float* ip = batch + j * 784;
        for (int k = t; k < 784; k += 256) img[k] = ip[k];
        __syncthreads();
        unsigned short* dst = Bmat + (size_t)j * 18432;
        for (int task = t; task < 2304; task += 256) {
            int c = task >> 2, kh = task & 3;
            int pp = c >> 2, q = c & 3;
            int py = pp / 12, px = pp - py * 12;
            int y0 = 2 * py + (q >> 1);
            int x0 = 2 * px + (q & 1);
            unsigned short ov[8] __attribute__((aligned(16)));
#pragma unroll
            for (int u = 0; u < 8; ++u) {
                int k = kh * 8 + u;
                float v = 0.f;
                if (k < 25) {
                    int ky = k / 5, kx = k - ky * 5;
                    v = img[(y0 + ky) * 28 + x0 + kx];
                }
                ov[u] = f2bf(v);
            }
            *(uint4*)(dst + c * 32 + kh * 8) = *(const uint4*)ov;
        }
    }
}

// ---------------- Kernel 1 (mega): conv1 + conv2 + pool + dense + log_softmax ----------------
// Block = (init i, image-group g of 4), 4 waves, wave w = image j = g*4+w.
// DISPATCH SWIZZLE (R10): i = blk & 63 (fast), g = blk >> 6 (slow):
//  - concurrent blocks on ALL XCDs share one 4-image Bmat slice (147 KB, L2-hot);
//    L3 refill ~8 XCD x 4.7 MB total instead of per-epoch thrash.
//  - XCD ~ blk%8 and i%8 == blk%8  =>  each XCD sees only 8 inits: its wswz
//    working set (205 KB) stays L2-resident for the entire kernel.
// BARRIER-FREE: every LDS byte a wave touches is its own slice; same-wave DS
// program order covers phase A->B; weights come from global (L2-resident).
#define A1_PIX_STRIDE 24        // elems (48 B)
#define IMG_LDS (144 * A1_PIX_STRIDE)   // 3456 elems = 6912 B per image
__global__ __launch_bounds__(256, 5) void mega_kernel(
        const float* __restrict__ params,
        const unsigned short* __restrict__ Bmat,   // [img][576][32] bf16 im2col
        const unsigned short* __restrict__ w1bf,   // [init][16][32] bf16
        const unsigned short* __restrict__ wswz,   // [init][25][32][16] bf16
        const unsigned short* __restrict__ w3l,    // [init][10][64][8] bf16 (permuted)
        float* __restrict__ out) {                 // [init][img][10] f32
    __shared__ unsigned short a1s[4 * IMG_LDS];    // 27648 B
    int b = blockIdx.x;
    int i = b & 63;           // init  (FAST dim -> XCD-local wswz residency)
    int g = b >> 6;           // image group (SLOW dim -> cross-XCD Bmat sharing)
    int t = threadIdx.x;
    int w = t >> 6;           // wave = image index within group
    int lane = t & 63;
    int j = g * 4 + w;

    // ---- Phase A: conv1 for (init i, image j), output -> own a1s slice ----
    {
        int co = lane & 15;       // conv1 out-channel = conv2 cin
        int h4 = lane >> 4;       // pool-quad row group
        short8 wfr = *(const short8*)(w1bf + (size_t)i * 512 + co * 32 + h4 * 8);
        float bias1 = params[(size_t)i * P_TOTAL + 400 + co];
        unsigned short* dst = a1s + w * IMG_LDS;
        const unsigned short* bsrc = Bmat + (size_t)j * 18432;
#pragma unroll 6
        for (int nt = 0; nt < 36; ++nt) {
            short8 afr = *(const short8*)(bsrc + (nt * 16 + co) * 32 + h4 * 8);
            float4v acc = {0.f, 0.f, 0.f, 0.f};
            acc = __builtin_amdgcn_mfma_f32_16x16x32_bf16(afr, wfr, acc, 0, 0, 0);
            float v = fmaxf(fmaxf(acc[0], acc[1]), fmaxf(acc[2], acc[3]));
            v = fmaxf(v + bias1, 0.f);
            dst[(nt * 4 + h4) * A1_PIX_STRIDE + co] = f2bf(v);   // pix = nt*4+h4
        }
    }
    // no barrier: this wave reads only its own writes (DS program order)

    // ---- Phase B: conv2, A = pixels (a1s), B = out-channels (wswz) ----
    int n = lane & 31;        // A row = pixel ; B col = co
    int h = lane >> 5;        // k-half
    const short8* wg = (const short8*)(wswz + (size_t)i * 12800 + n * 16 + h * 8);
    int y0 = n >> 3, x0 = n & 7;
    const unsigned short* bbase = a1s + w * IMG_LDS;
    const short8* pptr0 = (const short8*)(bbase + ((y0    ) * 12 + x0) * A1_PIX_STRIDE + h * 8);
    const short8* pptr1 = (const short8*)(bbase + ((y0 + 4) * 12 + x0) * A1_PIX_STRIDE + h * 8);

    float16 acc0 = {};   // D rows = pixels 0..31 (y 0..3), cols = co
    float16 acc1 = {};   // D rows = pixels 32..63 (y 4..7)
#pragma unroll
    for (int ky = 0; ky < 5; ++ky) {
#pragma unroll
        for (int kx = 0; kx < 5; ++kx) {
            int tap = ky * 5 + kx;
            short8 wf = wg[tap * 64];               // +tap*1024 B (global, L2)
            int bo = (ky * 12 + kx) * 3;
            short8 p0 = pptr0[bo];
            short8 p1 = pptr1[bo];
            acc0 = __builtin_amdgcn_mfma_f32_32x32x16_bf16(p0, wf, acc0, 0, 0, 0);
            acc1 = __builtin_amdgcn_mfma_f32_32x32x16_bf16(p1, wf, acc1, 0, 0, 0);
        }
    }

    // ---- Phase C: in-register 2x2 pool + bias + ReLU ----
    // row r = (reg&3) + 8*(reg>>2) + 4h -> pixel (y = p>>3, x = p&7).
    // pooled (pyl,d): regs {base, base+1, base+4, base+5}, base = pyl*8 + d*2.
    // lane (co = lane&31, h) ends with 8 features f = co*16 + py*4 + 2h + d,
    // slot s = py*2 + d  — matches w3l's prep permutation.
    int co2 = lane & 31;
    float bias2 = params[(size_t)i * P_TOTAL + 13216 + co2];
    float xr[8];
#pragma unroll
    for (int pyl = 0; pyl < 2; ++pyl) {
#pragma unroll
        for (int d = 0; d < 2; ++d) {
            int base = pyl * 8 + d * 2;
            float v0 = fmaxf(fmaxf(acc0[base], acc0[base + 1]),
                             fmaxf(acc0[base + 4], acc0[base + 5]));
            float v1 = fmaxf(fmaxf(acc1[base], acc1[base + 1]),
                             fmaxf(acc1[base + 4], acc1[base + 5]));
            xr[pyl * 2 + d]     = fmaxf(v0 + bias2, 0.f);   // py = pyl
            xr[4 + pyl * 2 + d] = fmaxf(v1 + bias2, 0.f);   // py = 2+pyl
        }
    }

    // ---- dense (10x512) + log_softmax; w3l permuted per-lane ----
    const unsigned short* w3p = w3l + (size_t)i * 5120 + lane * 8;
    float acc[10];
#pragma unroll
    for (int o = 0; o < 10; ++o) {
        uint4 u = *(const uint4*)(w3p + o * 512);
        float a = 0.f;
        a = fmaf(xr[0], bf2f((unsigned short)(u.x & 0xffffu)), a);
        a = fmaf(xr[1], bf2f((unsigned short)(u.x >> 16)), a);
        a = fmaf(xr[2], bf2f((unsigned short)(u.y & 0xffffu)), a);
        a = fmaf(xr[3], bf2f((unsigned short)(u.y >> 16)), a);
        a = fmaf(xr[4], bf2f((unsigned short)(u.z & 0xffffu)), a);
        a = fmaf(xr[5], bf2f((unsigned short)(u.z >> 16)), a);
        a = fmaf(xr[6], bf2f((unsigned short)(u.w & 0xffffu)), a);
        a = fmaf(xr[7], bf2f((unsigned short)(u.w >> 16)), a);
#pragma unroll
        for (int d = 32; d >= 1; d >>= 1) a += __shfl_xor(a, d, 64);
        acc[o] = a;
    }
    const float* bp = params + (size_t)i * P_TOTAL + 18368;
    float m = -3.4e38f;
#pragma unroll
    for (int o = 0; o < 10; ++o) { acc[o] += bp[o]; m = fmaxf(m, acc[o]); }
    float ssum = 0.f;
#pragma unroll
    for (int o = 0; o < 10; ++o) ssum += expf(acc[o] - m);
    float ls = logf(ssum) + m;
    if (lane == 0) {
        float* op = out + ((size_t)i * 128 + j) * 10;
#pragma unroll
        for (int o = 0; o < 10; ++o) op[o] = acc[o] - ls;
    }
}

extern "C" void kernel_launch(void* const* d_in, const int* in_sizes, int n_in,
                              void* d_out, int out_size, void* d_ws, size_t ws_size,
                              hipStream_t stream) {
    const float* params = (const float*)d_in[0];   // (64, 18378) fp32
    const float* batch  = (const float*)d_in[1];   // (128, 1, 28, 28) fp32
    float* out = (float*)d_out;                    // (64, 128, 10) fp32

    // workspace: wswz 1,638,400 B ; w3l 655,360 B ; w1bf 65,536 B ; Bmat 4,718,592 B
    unsigned short* wswz = (unsigned short*)d_ws;
    unsigned short* w3l  = wswz + (size_t)64 * 12800;
    unsigned short* w1bf = w3l + (size_t)64 * 5120;
    unsigned short* Bmat = w1bf + (size_t)64 * 512;

    prep_kernel<<<192, 256, 0, stream>>>(params, batch, wswz, w3l, w1bf, Bmat);
    mega_kernel<<<2048, 256, 0, stream>>>(params, Bmat, w1bf, wswz, w3l, out);
}